// Round 2
// baseline (312.828 us; speedup 1.0000x reference)
//
#include <hip/hip_runtime.h>

// MovingAvgNorm, LDS-tiled column-major: x (32,16384,80) fp32, k=100 reflect.
// Block = (batch, 512-step chunk, one of 5 groups of 16 channels), 512 threads.
// tile is COLUMN-major (tile[c][row], stride TILEP=614) so Phase C's three
// 8-row streams and the 100-row window init are all ds_read_b128,
// bank-conflict-free (2*614 % 32 == 12 spreads start banks across channels;
// worst aliasing is 2-way, which is free on CDNA4).
//
// R2 (fixes R1): window init must read 50 float4 (one float4 = TWO float2
// rows), not 25 — R1 summed only half the window. Structure otherwise as R1:
//  - no chunk-sum buffer / Phase B: LDS 49152 -> 39296 B = 4 blocks/CU
//    (24 -> 32 waves/CU), one barrier instead of two.
//  - chunked XCD swizzle: adjacent time-chunks (sharing the 100-row halo)
//    land on the same XCD -> halo refetch is an L2 hit.
//  - __launch_bounds__(512, 8) pins VGPR <= 64 so 8 waves/SIMD is reachable;
//    do NOT register-cache the init/slide overlapping reads (+32 VGPR would
//    drop to 7 waves/SIMD -> 3 blocks/CU).

namespace {

constexpr int K     = 100;
constexpr int HALF  = 50;
constexpr int Tn    = 16384;
constexpr int Bn    = 32;
constexpr int DGn   = 5;            // 5 groups of 8 float2 (16 floats)
constexpr int GC    = 8;            // float2 columns per group
constexpr int ROWF2 = 40;           // float2 per full 80-float row
constexpr int CTB   = 512;          // time steps per block
constexpr int NTC   = Tn / CTB;     // 32
constexpr int TILE  = CTB + K;      // 612 staged rows
constexpr int TILEP = 614;          // column stride (pad): 2*614 % 32 == 12
constexpr int CTT   = 8;            // outputs per thread
constexpr int TTn   = CTB / CTT;    // 64
constexpr int BLK   = TTn * GC;     // 512 threads
constexpr int NBLK  = Bn * NTC * DGn;  // 5120
constexpr int NXCD  = 8;
constexpr int PERX  = NBLK / NXCD;  // 640 (5120 % 8 == 0 -> bijective swizzle)
constexpr float C1  = 1.0f / (float)K;
constexpr float C2  = 1.0f / (float)(K - 1);

__device__ __forceinline__ float fast_rsqrt(float v) {
#if __has_builtin(__builtin_amdgcn_rsqf)
  return __builtin_amdgcn_rsqf(v);
#else
  return __frsqrt_rn(v);
#endif
}

__global__ __launch_bounds__(BLK, 8) void man_kernel(const float2* __restrict__ x,
                                                     float2* __restrict__ out) {
  __shared__ __align__(16) float2 tile[GC * TILEP];  // 39296 B -> 4 blk/CU

  const int tid = threadIdx.x;
  // Chunked XCD swizzle: hardware assigns dispatch d to XCD d%8; remap so
  // each XCD owns a contiguous range of work ids -> adjacent tc share L2.
  int blk = blockIdx.x;
  blk = (blk & (NXCD - 1)) * PERX + (blk >> 3);
  const int g   = blk % DGn;
  const int tc  = (blk / DGn) % NTC;
  const int b   = blk / (DGn * NTC);
  const int t0  = tc * CTB;

  const float2* __restrict__ xb = x   + (size_t)b * Tn * ROWF2 + g * GC;
  float2*       __restrict__ ob = out + (size_t)b * Tn * ROWF2 + g * GC;

  // ---- Phase A: stage rows [t0-50, t0+562) reflected; float4 global loads,
  //      transpose into column-major LDS via two b64 writes (bank-optimal). ----
  for (int w = tid; w < TILE * 4; w += BLK) {        // 2448 float4 jobs
    int r  = w >> 2;
    int c4 = w & 3;
    int gr = t0 - HALF + r;
    gr = (gr < 0) ? -gr : gr;
    gr = (gr >= Tn) ? 2 * (Tn - 1) - gr : gr;
    float4 v = *(const float4*)(xb + (size_t)gr * ROWF2 + c4 * 2);
    tile[(2 * c4)     * TILEP + r] = make_float2(v.x, v.y);
    tile[(2 * c4 + 1) * TILEP + r] = make_float2(v.z, v.w);
  }
  __syncthreads();

  // ---- Phase C: init window [tt*8, tt*8+100) = 50 float4 (2 rows each)
  //      straight from the tile column, then slide by 8 rows x 8 outputs. ----
  const int c  = tid & 7;
  const int tt = tid >> 3;

  const float2* tcol = tile + c * TILEP;

  float s1x = 0.f, s1y = 0.f, s2x = 0.f, s2y = 0.f;
  {
    const float4* ip = (const float4*)(tcol + tt * 8);
#pragma unroll
    for (int j = 0; j < 50; ++j) {
      float4 v = ip[j];                              // rows tt*8+2j, tt*8+2j+1
      s1x += v.x + v.z; s1y += v.y + v.w;
      s2x = fmaf(v.x, v.x, s2x); s2x = fmaf(v.z, v.z, s2x);
      s2y = fmaf(v.y, v.y, s2y); s2y = fmaf(v.w, v.w, s2y);
    }
  }

  const int rc0 = HALF + tt * 8;                     // tile row of output 0
  const float4* xc4 = (const float4*)(tcol + rc0);
  const float4* va4 = (const float4*)(tcol + rc0 + HALF);
  const float4* vs4 = (const float4*)(tcol + rc0 - HALF);
  float2* obase = ob + (size_t)(t0 + tt * 8) * ROWF2 + c;

#pragma unroll
  for (int m = 0; m < 4; ++m) {
    float4 xcp = xc4[m];
    float4 vap = va4[m];
    float4 vsp = vs4[m];
    // output row 2m (uses window state as-is)
    {
      float mx = s1x * C1, my = s1y * C1;
      float vx = fmaf(-s1x, mx, s2x) * C2;
      float vy = fmaf(-s1y, my, s2y) * C2;
      float rx = fast_rsqrt(fmaxf(vx, 1e-30f));
      float ry = fast_rsqrt(fmaxf(vy, 1e-30f));
      obase[(2 * m) * ROWF2] = make_float2((xcp.x - mx) * rx, (xcp.y - my) * ry);
    }
    s1x += vap.x - vsp.x; s1y += vap.y - vsp.y;
    s2x = fmaf(vap.x, vap.x, s2x); s2x = fmaf(-vsp.x, vsp.x, s2x);
    s2y = fmaf(vap.y, vap.y, s2y); s2y = fmaf(-vsp.y, vsp.y, s2y);
    // output row 2m+1
    {
      float mx = s1x * C1, my = s1y * C1;
      float vx = fmaf(-s1x, mx, s2x) * C2;
      float vy = fmaf(-s1y, my, s2y) * C2;
      float rx = fast_rsqrt(fmaxf(vx, 1e-30f));
      float ry = fast_rsqrt(fmaxf(vy, 1e-30f));
      obase[(2 * m + 1) * ROWF2] = make_float2((xcp.z - mx) * rx, (xcp.w - my) * ry);
    }
    s1x += vap.z - vsp.z; s1y += vap.w - vsp.w;
    s2x = fmaf(vap.z, vap.z, s2x); s2x = fmaf(-vsp.z, vsp.z, s2x);
    s2y = fmaf(vap.w, vap.w, s2y); s2y = fmaf(-vsp.w, vsp.w, s2y);
  }
}

}  // namespace

extern "C" void kernel_launch(void* const* d_in, const int* in_sizes, int n_in,
                              void* d_out, int out_size, void* d_ws, size_t ws_size,
                              hipStream_t stream) {
  (void)in_sizes; (void)n_in; (void)out_size; (void)d_ws; (void)ws_size;
  const float2* x = (const float2*)d_in[0];
  float2* o = (float2*)d_out;
  man_kernel<<<NBLK, BLK, 0, stream>>>(x, o);
}

// Round 3
// 312.338 us; speedup vs baseline: 1.0016x; 1.0016x over previous
//
#include <hip/hip_runtime.h>

// MovingAvgNorm, LDS-tiled column-major: x (32,16384,80) fp32, k=100 reflect.
// R3: back to R0's proven 3-phase structure (stage tile -> 8-row chunk sums ->
// slide), but with HALF-size blocks: GC=4 (8 channels), BLK=256, DGn=10.
// Per-thread work is identical to R0 in every phase; LDS per block drops
// 49152 -> 24576 B so 6 blocks/CU fit (24 waves) instead of 3 -- finer
// barrier granularity and 2x the independent blocks to overlap phases.
// Keeps R2's proven XCD swizzle (FETCH 195->111 MB): adjacent work ids
// (same rows, adjacent g / adjacent tc) land on one XCD's L2, so halo
// refetch and neighbor-g 32B segment halves merge there.
// tile is COLUMN-major (tile[c][row], stride TILEP=614): Phase B/C reads are
// ds_read_b128 with start banks (12c+16tt)%32 covering 8 distinct positions
// -> worst 2-way aliasing (free on CDNA4). cs stride NCHP=77 likewise.

namespace {

constexpr int K     = 100;
constexpr int HALF  = 50;
constexpr int Tn    = 16384;
constexpr int Bn    = 32;
constexpr int DGn   = 10;           // 10 groups of 4 float2 (8 floats)
constexpr int GC    = 4;            // float2 columns per group
constexpr int ROWF2 = 40;           // float2 per full 80-float row
constexpr int CTB   = 512;          // time steps per block
constexpr int NTC   = Tn / CTB;     // 32
constexpr int TILE  = CTB + K;      // 612 staged rows
constexpr int TILEP = 614;          // column stride (pad): 2*614 % 32 == 12
constexpr int CTT   = 8;            // outputs per thread
constexpr int TTn   = CTB / CTT;    // 64
constexpr int BLK   = TTn * GC;     // 256 threads
constexpr int NCH   = 75;           // 8-row chunk sums
constexpr int NCHP  = 77;           // chunk stride (pad): 4*77 % 32 == 20
constexpr int NBLK  = Bn * NTC * DGn;  // 10240
constexpr int NXCD  = 8;
constexpr int PERX  = NBLK / NXCD;  // 1280 (10240 % 8 == 0 -> bijective)
constexpr float C1  = 1.0f / (float)K;
constexpr float C2  = 1.0f / (float)(K - 1);

__device__ __forceinline__ float fast_rsqrt(float v) {
#if __has_builtin(__builtin_amdgcn_rsqf)
  return __builtin_amdgcn_rsqf(v);
#else
  return __frsqrt_rn(v);
#endif
}

__global__ __launch_bounds__(BLK, 6) void man_kernel(const float2* __restrict__ x,
                                                     float2* __restrict__ out) {
  __shared__ __align__(16) float2 tile[GC * TILEP];  // 19648 B
  __shared__ float4 cs[GC * NCHP];                   // 4928 B -> 24576 B, 6 blk/CU

  const int tid = threadIdx.x;
  // Chunked XCD swizzle: hardware sends dispatch d to XCD d%8; remap so each
  // XCD owns a contiguous range of work ids -> neighbors share its L2.
  int blk = blockIdx.x;
  blk = (blk & (NXCD - 1)) * PERX + (blk >> 3);
  const int g   = blk % DGn;
  const int tc  = (blk / DGn) % NTC;
  const int b   = blk / (DGn * NTC);
  const int t0  = tc * CTB;

  const float2* __restrict__ xb = x   + (size_t)b * Tn * ROWF2 + g * GC;
  float2*       __restrict__ ob = out + (size_t)b * Tn * ROWF2 + g * GC;

  // ---- Phase A: stage rows [t0-50, t0+562) reflected; float4 global loads,
  //      transpose into column-major LDS via two b64 writes. ----
  for (int w = tid; w < TILE * 2; w += BLK) {        // 1224 float4 jobs
    int r  = w >> 1;
    int c4 = w & 1;
    int gr = t0 - HALF + r;
    gr = (gr < 0) ? -gr : gr;
    gr = (gr >= Tn) ? 2 * (Tn - 1) - gr : gr;
    float4 v = *(const float4*)(xb + (size_t)gr * ROWF2 + c4 * 2);
    tile[(2 * c4)     * TILEP + r] = make_float2(v.x, v.y);
    tile[(2 * c4 + 1) * TILEP + r] = make_float2(v.z, v.w);
  }
  __syncthreads();

  // ---- Phase B: 8-row chunk sums, stored as float4(s1x,s1y,s2x,s2y) ----
  for (int job = tid; job < NCH * GC; job += BLK) {  // 300 jobs
    int c = job & 3;
    int q = job >> 2;
    const float4* tp = (const float4*)(tile + c * TILEP + q * 8);
    float s1x = 0.f, s1y = 0.f, s2x = 0.f, s2y = 0.f;
#pragma unroll
    for (int m = 0; m < 4; ++m) {
      float4 v = tp[m];                              // rows q*8+2m, q*8+2m+1
      s1x += v.x + v.z; s1y += v.y + v.w;
      s2x = fmaf(v.x, v.x, s2x); s2x = fmaf(v.z, v.z, s2x);
      s2y = fmaf(v.y, v.y, s2y); s2y = fmaf(v.w, v.w, s2y);
    }
    cs[c * NCHP + q] = make_float4(s1x, s1y, s2x, s2y);
  }
  __syncthreads();

  // ---- Phase C: init window [tt*8, tt*8+100) = 12 chunks + 4 rows, slide 8 ----
  const int c  = tid & 3;
  const int tt = tid >> 2;

  float s1x = 0.f, s1y = 0.f, s2x = 0.f, s2y = 0.f;
  const float4* cp = cs + c * NCHP + tt;
#pragma unroll
  for (int j = 0; j < 12; ++j) {
    float4 a = cp[j];
    s1x += a.x; s1y += a.y; s2x += a.z; s2y += a.w;
  }
  const float2* tcol = tile + c * TILEP;
  {
    const float4* e4 = (const float4*)(tcol + tt * 8 + 96);
#pragma unroll
    for (int m = 0; m < 2; ++m) {
      float4 v = e4[m];
      s1x += v.x + v.z; s1y += v.y + v.w;
      s2x = fmaf(v.x, v.x, s2x); s2x = fmaf(v.z, v.z, s2x);
      s2y = fmaf(v.y, v.y, s2y); s2y = fmaf(v.w, v.w, s2y);
    }
  }

  const int rc0 = HALF + tt * 8;                     // tile row of output 0
  const float4* xc4 = (const float4*)(tcol + rc0);
  const float4* va4 = (const float4*)(tcol + rc0 + HALF);
  const float4* vs4 = (const float4*)(tcol + rc0 - HALF);
  float2* obase = ob + (size_t)(t0 + tt * 8) * ROWF2 + c;

#pragma unroll
  for (int m = 0; m < 4; ++m) {
    float4 xcp = xc4[m];
    float4 vap = va4[m];
    float4 vsp = vs4[m];
    // output row 2m (uses window state as-is)
    {
      float mx = s1x * C1, my = s1y * C1;
      float vx = fmaf(-s1x, mx, s2x) * C2;
      float vy = fmaf(-s1y, my, s2y) * C2;
      float rx = fast_rsqrt(fmaxf(vx, 1e-30f));
      float ry = fast_rsqrt(fmaxf(vy, 1e-30f));
      obase[(2 * m) * ROWF2] = make_float2((xcp.x - mx) * rx, (xcp.y - my) * ry);
    }
    s1x += vap.x - vsp.x; s1y += vap.y - vsp.y;
    s2x = fmaf(vap.x, vap.x, s2x); s2x = fmaf(-vsp.x, vsp.x, s2x);
    s2y = fmaf(vap.y, vap.y, s2y); s2y = fmaf(-vsp.y, vsp.y, s2y);
    // output row 2m+1
    {
      float mx = s1x * C1, my = s1y * C1;
      float vx = fmaf(-s1x, mx, s2x) * C2;
      float vy = fmaf(-s1y, my, s2y) * C2;
      float rx = fast_rsqrt(fmaxf(vx, 1e-30f));
      float ry = fast_rsqrt(fmaxf(vy, 1e-30f));
      obase[(2 * m + 1) * ROWF2] = make_float2((xcp.z - mx) * rx, (xcp.w - my) * ry);
    }
    s1x += vap.z - vsp.z; s1y += vap.w - vsp.w;
    s2x = fmaf(vap.z, vap.z, s2x); s2x = fmaf(-vsp.z, vsp.z, s2x);
    s2y = fmaf(vap.w, vap.w, s2y); s2y = fmaf(-vsp.w, vsp.w, s2y);
  }
}

}  // namespace

extern "C" void kernel_launch(void* const* d_in, const int* in_sizes, int n_in,
                              void* d_out, int out_size, void* d_ws, size_t ws_size,
                              hipStream_t stream) {
  (void)in_sizes; (void)n_in; (void)out_size; (void)d_ws; (void)ws_size;
  const float2* x = (const float2*)d_in[0];
  float2* o = (float2*)d_out;
  man_kernel<<<NBLK, BLK, 0, stream>>>(x, o);
}

// Round 4
// 298.435 us; speedup vs baseline: 1.0482x; 1.0466x over previous
//
#include <hip/hip_runtime.h>

// MovingAvgNorm, LDS-tiled column-major: x (32,16384,80) fp32, k=100 reflect.
// R4 = R0 structure (stage -> 8-row chunk sums -> slide; GC=8, 512 threads,
// 3 blocks/CU, NO xcd swizzle -- swizzle cost ~10us in R2/R3) with ONE change:
// Phase A is padded to 640 staged rows so every thread does exactly 5 load
// jobs -> fully unrolled -> 5 independent global_load_dwordx4 in flight per
// wave instead of 1 (rolled loop serialized on vmcnt(0)). Little's law: 24
// waves x 1KB = 24KB/CU was right at the ~22KB needed to cover ~900cy HBM
// latency; 5x fixes the load-latency limit seen as hbm_gbps ~52% of achievable.
// TILEP 614->642 (2*642%32==4): all Phase A/B/C access patterns re-checked,
// worst aliasing 2-way (free). Rows 612..639 are junk (valid clamped reflect
// reads) and are never read by Phase B (rows<600) or C (rows<612).

namespace {

constexpr int K     = 100;
constexpr int HALF  = 50;
constexpr int Tn    = 16384;
constexpr int Bn    = 32;
constexpr int DGn   = 5;            // 5 groups of 8 float2 (16 floats)
constexpr int GC    = 8;            // float2 columns per group
constexpr int ROWF2 = 40;           // float2 per full 80-float row
constexpr int CTB   = 512;          // time steps per block
constexpr int NTC   = Tn / CTB;     // 32
constexpr int TILE  = CTB + K;      // 612 rows actually used
constexpr int TILER = 640;          // staged rows, padded: 640*4 = 5*512 jobs
constexpr int TILEP = 642;          // column stride: 2*642 % 32 == 4
constexpr int AUNR  = (TILER * 4) / 512;  // 5 uniform jobs/thread
constexpr int CTT   = 8;            // outputs per thread
constexpr int TTn   = CTB / CTT;    // 64
constexpr int BLK   = TTn * GC;     // 512 threads
constexpr int NCH   = 75;           // 8-row chunk sums
constexpr int NCHP  = 77;           // chunk stride (pad): 4*77 % 32 == 20
constexpr int NBLK  = Bn * NTC * DGn;  // 5120
constexpr float C1  = 1.0f / (float)K;
constexpr float C2  = 1.0f / (float)(K - 1);

__device__ __forceinline__ float fast_rsqrt(float v) {
#if __has_builtin(__builtin_amdgcn_rsqf)
  return __builtin_amdgcn_rsqf(v);
#else
  return __frsqrt_rn(v);
#endif
}

__global__ __launch_bounds__(BLK, 6) void man_kernel(const float2* __restrict__ x,
                                                     float2* __restrict__ out) {
  __shared__ __align__(16) float2 tile[GC * TILEP];  // 41088 B
  __shared__ float4 cs[GC * NCHP];                   // 9856 B -> 50944 B, 3 blk/CU

  const int tid = threadIdx.x;
  const int blk = blockIdx.x;                        // no swizzle (R2/R3 lesson)
  const int g   = blk % DGn;
  const int tc  = (blk / DGn) % NTC;
  const int b   = blk / (DGn * NTC);
  const int t0  = tc * CTB;

  const float2* __restrict__ xb = x   + (size_t)b * Tn * ROWF2 + g * GC;
  float2*       __restrict__ ob = out + (size_t)b * Tn * ROWF2 + g * GC;

  // ---- Phase A: stage rows [t0-50, t0+590) reflected. Uniform 5 jobs per
  //      thread, fully unrolled: all 5 global_load_dwordx4 issue before the
  //      first ds_write waits (staged vmcnt), 5x in-flight bytes per wave. ----
  float4 av[AUNR];
#pragma unroll
  for (int u = 0; u < AUNR; ++u) {
    int w  = tid + u * BLK;
    int r  = w >> 2;
    int c4 = w & 3;
    int gr = t0 - HALF + r;
    gr = (gr < 0) ? -gr : gr;
    gr = (gr >= Tn) ? 2 * (Tn - 1) - gr : gr;
    av[u] = *(const float4*)(xb + (size_t)gr * ROWF2 + c4 * 2);
  }
#pragma unroll
  for (int u = 0; u < AUNR; ++u) {
    int w  = tid + u * BLK;
    int r  = w >> 2;
    int c4 = w & 3;
    tile[(2 * c4)     * TILEP + r] = make_float2(av[u].x, av[u].y);
    tile[(2 * c4 + 1) * TILEP + r] = make_float2(av[u].z, av[u].w);
  }
  __syncthreads();

  // ---- Phase B: 8-row chunk sums, stored as float4(s1x,s1y,s2x,s2y) ----
  for (int job = tid; job < NCH * GC; job += BLK) {  // 600 jobs
    int c = job & 7;
    int q = job >> 3;
    const float4* tp = (const float4*)(tile + c * TILEP + q * 8);
    float s1x = 0.f, s1y = 0.f, s2x = 0.f, s2y = 0.f;
#pragma unroll
    for (int m = 0; m < 4; ++m) {
      float4 v = tp[m];                              // rows q*8+2m, q*8+2m+1
      s1x += v.x + v.z; s1y += v.y + v.w;
      s2x = fmaf(v.x, v.x, s2x); s2x = fmaf(v.z, v.z, s2x);
      s2y = fmaf(v.y, v.y, s2y); s2y = fmaf(v.w, v.w, s2y);
    }
    cs[c * NCHP + q] = make_float4(s1x, s1y, s2x, s2y);
  }
  __syncthreads();

  // ---- Phase C: init window [tt*8, tt*8+100) = 12 chunks + 4 rows, slide 8 ----
  const int c  = tid & 7;
  const int tt = tid >> 3;

  float s1x = 0.f, s1y = 0.f, s2x = 0.f, s2y = 0.f;
  const float4* cp = cs + c * NCHP + tt;
#pragma unroll
  for (int j = 0; j < 12; ++j) {
    float4 a = cp[j];
    s1x += a.x; s1y += a.y; s2x += a.z; s2y += a.w;
  }
  const float2* tcol = tile + c * TILEP;
  {
    const float4* e4 = (const float4*)(tcol + tt * 8 + 96);
#pragma unroll
    for (int m = 0; m < 2; ++m) {
      float4 v = e4[m];
      s1x += v.x + v.z; s1y += v.y + v.w;
      s2x = fmaf(v.x, v.x, s2x); s2x = fmaf(v.z, v.z, s2x);
      s2y = fmaf(v.y, v.y, s2y); s2y = fmaf(v.w, v.w, s2y);
    }
  }

  const int rc0 = HALF + tt * 8;                     // tile row of output 0
  const float4* xc4 = (const float4*)(tcol + rc0);
  const float4* va4 = (const float4*)(tcol + rc0 + HALF);
  const float4* vs4 = (const float4*)(tcol + rc0 - HALF);
  float2* obase = ob + (size_t)(t0 + tt * 8) * ROWF2 + c;

#pragma unroll
  for (int m = 0; m < 4; ++m) {
    float4 xcp = xc4[m];
    float4 vap = va4[m];
    float4 vsp = vs4[m];
    // output row 2m (uses window state as-is)
    {
      float mx = s1x * C1, my = s1y * C1;
      float vx = fmaf(-s1x, mx, s2x) * C2;
      float vy = fmaf(-s1y, my, s2y) * C2;
      float rx = fast_rsqrt(fmaxf(vx, 1e-30f));
      float ry = fast_rsqrt(fmaxf(vy, 1e-30f));
      obase[(2 * m) * ROWF2] = make_float2((xcp.x - mx) * rx, (xcp.y - my) * ry);
    }
    s1x += vap.x - vsp.x; s1y += vap.y - vsp.y;
    s2x = fmaf(vap.x, vap.x, s2x); s2x = fmaf(-vsp.x, vsp.x, s2x);
    s2y = fmaf(vap.y, vap.y, s2y); s2y = fmaf(-vsp.y, vsp.y, s2y);
    // output row 2m+1
    {
      float mx = s1x * C1, my = s1y * C1;
      float vx = fmaf(-s1x, mx, s2x) * C2;
      float vy = fmaf(-s1y, my, s2y) * C2;
      float rx = fast_rsqrt(fmaxf(vx, 1e-30f));
      float ry = fast_rsqrt(fmaxf(vy, 1e-30f));
      obase[(2 * m + 1) * ROWF2] = make_float2((xcp.z - mx) * rx, (xcp.w - my) * ry);
    }
    s1x += vap.z - vsp.z; s1y += vap.w - vsp.w;
    s2x = fmaf(vap.z, vap.z, s2x); s2x = fmaf(-vsp.z, vsp.z, s2x);
    s2y = fmaf(vap.w, vap.w, s2y); s2y = fmaf(-vsp.w, vsp.w, s2y);
  }
}

}  // namespace

extern "C" void kernel_launch(void* const* d_in, const int* in_sizes, int n_in,
                              void* d_out, int out_size, void* d_ws, size_t ws_size,
                              hipStream_t stream) {
  (void)in_sizes; (void)n_in; (void)out_size; (void)d_ws; (void)ws_size;
  const float2* x = (const float2*)d_in[0];
  float2* o = (float2*)d_out;
  man_kernel<<<NBLK, BLK, 0, stream>>>(x, o);
}